// Round 12
// baseline (311.566 us; speedup 1.0000x reference)
//
#include <hip/hip_runtime.h>
#include <math.h>

#define NPTS  16384
#define KNN   16
#define SEQV  8
#define NW    16      // waves per block
#define QB    64      // queries per block (lane = query)
#define SLICE 1024    // candidates per wave slice (NW*SLICE = NPTS)
#define SAMP  128     // sampled per slice -> global 2048-sample
#define BATCH 8
#define CAPT  15      // append words/thread; odd stride -> conflict-free

__device__ __forceinline__ unsigned umin_(unsigned a, unsigned b) { return a < b ? a : b; }
__device__ __forceinline__ unsigned umax_(unsigned a, unsigned b) { return a > b ? a : b; }

// merge one key into sorted ascending keys[16]
__device__ __forceinline__ void merge_one(unsigned keys[KNN], unsigned kk) {
    if (kk < keys[KNN - 1]) {
#pragma unroll
        for (int u = 0; u < KNN; ++u) {
            unsigned lo = umin_(kk, keys[u]);
            kk = umax_(kk, keys[u]);
            keys[u] = lo;
        }
    }
}

// ---------------------------------------------------------------------------
// K0: pc4[i] = (x,y,z,|c|^2); thread 0 zeroes accum (loss, wsum, ticket).
// ---------------------------------------------------------------------------
__global__ __launch_bounds__(256) void pc4_kernel(
    const float* __restrict__ pc, float4* __restrict__ pc4,
    float* __restrict__ accum)
{
    const int i = blockIdx.x * 256 + threadIdx.x;
    float x = pc[3 * i + 0], y = pc[3 * i + 1], z = pc[3 * i + 2];
    pc4[i] = make_float4(x, y, z, fmaf(x, x, fmaf(y, y, z * z)));
    if (i == 0) {
        accum[0] = 0.0f; accum[1] = 0.0f;
        ((unsigned*)accum)[2] = 0u; ((unsigned*)accum)[3] = 0u;
    }
}

// ---------------------------------------------------------------------------
// K1: mega kernel. Grid 256 x 1024 (1 block/CU, 4 waves/SIMD).
// Block owns queries [64*bx, 64*bx+64); wave wv owns slice [1024*wv, +1024).
// A: sample first 128 of slice (cold chain) -> lists in block-local scratch
// B: tree merge (4 rounds) -> tau per query (exact filter bound)
// C: R9-style filtered scan -> fresh per-slice lists in scratch
// D: tree merge + radius -> ids[64][16] in LDS
// E: loss gathers + block reduce + ticket finalize
// key = (d2 bits & 0xFFFFC000) | j  (j < 2^14).
// ---------------------------------------------------------------------------
__global__ __launch_bounds__(1024, 4) void mega_kernel(
    const float4* __restrict__ pc4, const float* __restrict__ flow,
    const float* __restrict__ wts, unsigned* __restrict__ scratch,
    float* __restrict__ accum, float* __restrict__ out)
{
    __shared__ unsigned uS[CAPT * 1024];   // 61.4 KB union region
    __shared__ float sTau[QB];
    __shared__ float sred[NW];

    const int tid  = threadIdx.x;
    const int lane = tid & 63;
    const int wv   = tid >> 6;             // 0..15
    const int bx   = blockIdx.x;
    const int i    = bx * QB + lane;       // this lane's query

    const float4 qv = pc4[i];
    unsigned* listsG = scratch + (size_t)bx * (NW * QB * KNN);  // 64 KB/block

    const int jbeg = wv * SLICE;
    const float4* cb = pc4 + jbeg;         // wave-uniform -> s_load bursts

    unsigned keys[KNN];

    // ================= Phase A: sample scan (first SAMP) ===================
    {
#pragma unroll
        for (int t = 0; t < KNN; ++t) keys[t] = 0xFFFFFFFFu;

        float4 A[BATCH], B[BATCH];
#pragma unroll
        for (int q = 0; q < BATCH; ++q) A[q] = cb[q];

        auto processA = [&](const float4* C, int jbase) {
            unsigned kb[BATCH];
#pragma unroll
            for (int q = 0; q < BATCH; ++q) {
                const float4 c = C[q];
                float dot = fmaf(c.x, qv.x, fmaf(c.y, qv.y, c.z * qv.z));
                float d2p = fmaf(-2.0f, dot, c.w);
                float d2  = fmaxf(d2p + qv.w, 0.0f);
                kb[q] = (__float_as_uint(d2) & 0xFFFFC000u)
                      | (unsigned)(jbeg + jbase + q);
            }
#pragma unroll
            for (int q = 0; q < BATCH; ++q) merge_one(keys, kb[q]);
        };

#pragma unroll 1
        for (int jo = 0; jo < SAMP; jo += 2 * BATCH) {
#pragma unroll
            for (int q = 0; q < BATCH; ++q) B[q] = cb[jo + BATCH + q];
            processA(A, jo);
            if (jo + 2 * BATCH < SAMP) {
#pragma unroll
                for (int q = 0; q < BATCH; ++q) A[q] = cb[jo + 2 * BATCH + q];
            }
            processA(B, jo + BATCH);
        }

        unsigned* dst = listsG + (wv * QB + lane) * KNN;
#pragma unroll
        for (int t = 0; t < KNN; ++t) dst[t] = keys[t];
    }
    __syncthreads();

    // 4-round tree merge of the 16 per-slice lists (round 1 from global,
    // rounds 2-4 via LDS stride-17 slots). Result in wave 0's keys[].
    auto tree_merge = [&]() {
        if (wv < 8) {
            const unsigned* l0 = listsG + (wv * QB + lane) * KNN;
            const unsigned* l1 = listsG + ((wv + 8) * QB + lane) * KNN;
#pragma unroll
            for (int t = 0; t < KNN; ++t) keys[t] = l0[t];
#pragma unroll
            for (int t = 0; t < KNN; ++t) merge_one(keys, l1[t]);
            unsigned* s = &uS[(wv * QB + lane) * 17];
#pragma unroll
            for (int t = 0; t < KNN; ++t) s[t] = keys[t];
        }
        __syncthreads();
        if (wv < 4) {
            const unsigned* p = &uS[((wv + 4) * QB + lane) * 17];
#pragma unroll
            for (int t = 0; t < KNN; ++t) merge_one(keys, p[t]);
            unsigned* s = &uS[(wv * QB + lane) * 17];
#pragma unroll
            for (int t = 0; t < KNN; ++t) s[t] = keys[t];
        }
        __syncthreads();
        if (wv < 2) {
            const unsigned* p = &uS[((wv + 2) * QB + lane) * 17];
#pragma unroll
            for (int t = 0; t < KNN; ++t) merge_one(keys, p[t]);
            unsigned* s = &uS[(wv * QB + lane) * 17];
#pragma unroll
            for (int t = 0; t < KNN; ++t) s[t] = keys[t];
        }
        __syncthreads();
        if (wv == 0) {
            const unsigned* p = &uS[(1 * QB + lane) * 17];
#pragma unroll
            for (int t = 0; t < KNN; ++t) merge_one(keys, p[t]);
        }
    };

    // ================= Phase B: tau from the 2048-sample ===================
    tree_merge();
    if (wv == 0) {
        const float d16 = __uint_as_float(keys[KNN - 1] & 0xFFFFC000u);
        sTau[lane] = fmaf(d16, 1.0002f, 1e-6f) - qv.w;   // margin -> exact
    }
    __syncthreads();

    // ================= Phase C: filtered main scan =========================
    {
        float tauf = sTau[lane];
#pragma unroll
        for (int t = 0; t < KNN; ++t) keys[t] = 0xFFFFFFFFu;
        int cnt = 0;
        unsigned* buf = &uS[tid * CAPT];

        float4 A[BATCH], B[BATCH];
#pragma unroll
        for (int q = 0; q < BATCH; ++q) A[q] = cb[q];

        auto processC = [&](const float4* C, int jbase) {
#pragma unroll
            for (int q = 0; q < BATCH; ++q) {
                const float4 c = C[q];
                float dot = fmaf(c.x, qv.x, fmaf(c.y, qv.y, c.z * qv.z));
                float d2p = fmaf(-2.0f, dot, c.w);     // d2 - |q|^2
                if (d2p <= tauf) {                     // exec-masked accept
                    float d2 = fmaxf(d2p + qv.w, 0.0f);
                    buf[cnt] = (__float_as_uint(d2) & 0xFFFFC000u)
                             | (unsigned)(jbeg + jbase + q);
                    ++cnt;
                }
            }
            // headroom: enter batch with cnt <= 6 -> max idx 14 < CAPT
            if (cnt >= CAPT - BATCH) {
#pragma unroll 1
                for (int t = 0; t < cnt; ++t) merge_one(keys, buf[t]);
                cnt = 0;
                float d16n = __uint_as_float(keys[KNN - 1] & 0xFFFFC000u);
                tauf = fminf(tauf, fmaf(d16n, 1.0002f, 1e-6f) - qv.w);
            }
        };

#pragma unroll 1
        for (int jo = 0; jo < SLICE; jo += 2 * BATCH) {
#pragma unroll
            for (int q = 0; q < BATCH; ++q) B[q] = cb[jo + BATCH + q];
            processC(A, jo);
            if (jo + 2 * BATCH < SLICE) {
#pragma unroll
                for (int q = 0; q < BATCH; ++q) A[q] = cb[jo + 2 * BATCH + q];
            }
            processC(B, jo + BATCH);
        }
#pragma unroll 1
        for (int t = 0; t < cnt; ++t) merge_one(keys, buf[t]);

        unsigned* dst = listsG + (wv * QB + lane) * KNN;   // overwrite sample
#pragma unroll
        for (int t = 0; t < KNN; ++t) dst[t] = keys[t];
    }
    __syncthreads();

    // ================= Phase D: final merge + radius -> ids ================
    tree_merge();
    if (wv == 0) {
        const int id0 = (int)(keys[0] & 0x3FFFu);   // nearest (self)
#pragma unroll
        for (int t = 0; t < KNN; ++t) {
            float d2t = __uint_as_float(keys[t] & 0xFFFFC000u);
            int   j   = (int)(keys[t] & 0x3FFFu);
            uS[lane * 17 + t] = (unsigned)((d2t > 1.0f) ? id0 : j);
        }
    }
    __syncthreads();

    // ================= Phase E: loss + reduce + finalize ===================
    {
        const int s  = wv & 7;
        const int kh = wv >> 3;
        const float* fs = flow + (size_t)s * NPTS * 3;
        const float fx = fs[3 * i + 0];
        const float fy = fs[3 * i + 1];
        const float fz = fs[3 * i + 2];

        float sum = 0.0f;
#pragma unroll
        for (int z = 0; z < 8; ++z) {
            int j = (int)uS[lane * 17 + kh * 8 + z];
            float dx = fx - fs[3 * j + 0];
            float dy = fy - fs[3 * j + 1];
            float dz = fz - fs[3 * j + 2];
            float sq = fmaf(dx, dx, fmaf(dy, dy, dz * dz));
            sum += (sq > 0.0f) ? sqrtf(sq) : 0.0f;
        }

        float contrib = wts[i] * sum;
#pragma unroll
        for (int off = 32; off > 0; off >>= 1) contrib += __shfl_down(contrib, off);
        if (lane == 0) sred[wv] = contrib;

        if (wv == 0) {                       // weight sum, once per block
            float wi = wts[i];
#pragma unroll
            for (int off = 32; off > 0; off >>= 1) wi += __shfl_down(wi, off);
            if (lane == 0) atomicAdd(&accum[1], wi);
        }
        __syncthreads();

        if (tid == 0) {
            float c = 0.0f;
#pragma unroll
            for (int t = 0; t < NW; ++t) c += sred[t];
            atomicAdd(&accum[0], c);
            __threadfence();
            unsigned ticket = atomicAdd((unsigned*)&accum[2], 1u);
            if (ticket == gridDim.x - 1) {   // last block finalizes
                float a  = atomicAdd(&accum[0], 0.0f);   // coherent read
                float ws = atomicAdd(&accum[1], 0.0f);
                float v  = a / (float)(KNN * SEQV);
                out[0] = (ws > 0.0f) ? (v / ws) : v;
            }
        }
    }
}

extern "C" void kernel_launch(void* const* d_in, const int* in_sizes, int n_in,
                              void* d_out, int out_size, void* d_ws, size_t ws_size,
                              hipStream_t stream)
{
    const float* pc   = (const float*)d_in[0];   // (1, N, 3)
    const float* flow = (const float*)d_in[1];   // (SEQ, N, 3)
    const float* wts  = (const float*)d_in[2];   // (N,)
    float* out = (float*)d_out;

    // layout: accum(256 B) | pc4(256 KB) | scratch lists (16.8 MB)
    float*    accum   = (float*)d_ws;
    float4*   pc4     = (float4*)((char*)d_ws + 256);
    unsigned* scratch = (unsigned*)((char*)d_ws + 256 + NPTS * 16);

    pc4_kernel<<<NPTS / 256, 256, 0, stream>>>(pc, pc4, accum);
    mega_kernel<<<NPTS / QB, 1024, 0, stream>>>(pc4, flow, wts, scratch, accum, out);
}